// Round 1
// baseline (190.440 us; speedup 1.0000x reference)
//
#include <hip/hip_runtime.h>

// Sizes (fixed for this problem)
constexpr int B  = 2,  CIN = 2,  H = 64, W = 64, T = 350;
constexpr int C1 = 8;                       // conv1 out channels
constexpr int CO = 2,  TO = 700, HO = 128, WO = 64;
constexpr int HW = H * W;                   // 4096

#define DEC 0.05000000074505806f            // (float)(1.0 - 0.95)

// ---------------------------------------------------------------------------
// Kernel 0: transpose x [B,2,H,W,T] -> xT [B,2,T,H,W] so conv reads coalesce.
// ---------------------------------------------------------------------------
__global__ void __launch_bounds__(256) transpose_kernel(
    const float* __restrict__ x, float* __restrict__ xT) {
  __shared__ float tile[64][65];
  int bid   = blockIdx.x;
  int tTile = bid % 6;            // 6 tiles of 64 cover T=350
  int slice = bid / 6;            // (b*2+ci)*64 + h
  int h  = slice % H;
  int bc = slice / H;             // b*2+ci
  int t0 = tTile * 64;
  int tx = threadIdx.x & 63;
  int tz = threadIdx.x >> 6;      // 0..3

  const float* src = x + ((long)bc * H + h) * (long)(W * T);
#pragma unroll
  for (int i = 0; i < 16; ++i) {
    int w = tz * 16 + i;
    int t = t0 + tx;
    tile[w][tx] = (t < T) ? src[(long)w * T + t] : 0.0f;
  }
  __syncthreads();
  float* dst = xT + ((long)bc * T) * HW + h * 64;
#pragma unroll
  for (int i = 0; i < 16; ++i) {
    int tl = tz * 16 + i;
    int t  = t0 + tl;
    if (t < T) dst[(long)t * HW + tx] = tile[tx][tl];
  }
}

// ---------------------------------------------------------------------------
// Kernel A: conv1(5x5 over T,H) + bias + relu + LIF1 + delta -> d8 int8
// block = 512 threads = (co 0..7) x (w 0..63), fixed (b,h,chunk).
// T chunked in 2 with 30-step warm-up (0.05^30 -> bitwise converged state).
// ---------------------------------------------------------------------------
__global__ void __launch_bounds__(512, 2) convlif_kernel(
    const float* __restrict__ xT, const float* __restrict__ w1,
    const float* __restrict__ b1, signed char* __restrict__ d8) {
  int bid   = blockIdx.x;
  int chunk = bid & 1;
  int rest  = bid >> 1;
  int h = rest & 63;
  int b = rest >> 6;
  int w  = threadIdx.x & 63;
  int co = threadIdx.x >> 6;

  // Weights for this co; zero rows whose h+dh-2 is out of range so clamped
  // loads contribute nothing.
  float wt[2][5][5];
#pragma unroll
  for (int ci = 0; ci < 2; ++ci)
#pragma unroll
    for (int dt = 0; dt < 5; ++dt)
#pragma unroll
      for (int dh = 0; dh < 5; ++dh)
        wt[ci][dt][dh] = w1[((co * 2 + ci) * 5 + dt) * 5 + dh];
  float bias = b1[co];

  const float* base[2][5];
#pragma unroll
  for (int ci = 0; ci < 2; ++ci)
#pragma unroll
    for (int dh = 0; dh < 5; ++dh) {
      int hh = h + dh - 2;
      bool hv = (hh >= 0) && (hh < H);
      int hc = hh < 0 ? 0 : (hh >= H ? H - 1 : hh);
      base[ci][dh] = xT + ((long)((b * 2 + ci) * T)) * HW + hc * 64 + w;
      if (!hv) {
#pragma unroll
        for (int dt = 0; dt < 5; ++dt) wt[ci][dt][dh] = 0.0f;
      }
    }

  // chunk 0: t in [0,175) stored; chunk 1: warm [145,175), stored [175,350).
  int ts     = chunk ? 145 : 0;     // multiple of 5 (slot math needs ts%5==0)
  int tstore = chunk ? 175 : 0;
  int te     = chunk ? 350 : 175;

  // Sliding window win[ci][dh][slot], slot = tau % 5.
  float win[2][5][5];
#pragma unroll
  for (int ci = 0; ci < 2; ++ci)
#pragma unroll
    for (int dh = 0; dh < 5; ++dh) {
      const float* bp = base[ci][dh];
      win[ci][dh][3] = (ts >= 2) ? bp[(long)(ts - 2) * HW] : 0.0f;
      win[ci][dh][4] = (ts >= 1) ? bp[(long)(ts - 1) * HW] : 0.0f;
      win[ci][dh][0] = bp[(long)(ts + 0) * HW];
      win[ci][dh][1] = bp[(long)(ts + 1) * HW];
      win[ci][dh][2] = bp[(long)(ts + 2) * HW];
    }

  signed char* dsto = d8 + ((long)(b * C1 + co) * T) * HW + h * 64 + w;

  float y = 0.0f, sprev = 0.0f;
  for (int tb = ts; tb < te; tb += 5) {
#pragma unroll
    for (int u = 0; u < 5; ++u) {
      int t = tb + u;
      float ac0 = 0.f, ac1 = 0.f, ac2 = 0.f, ac3 = 0.f;
#pragma unroll
      for (int ci = 0; ci < 2; ++ci)
#pragma unroll
        for (int dt = 0; dt < 5; ++dt) {
          const int slot = (u + dt + 3) % 5;
#pragma unroll
          for (int dh = 0; dh < 5; ++dh) {
            const int q = (ci * 25 + dt * 5 + dh) & 3;
            float p = win[ci][dh][slot] * wt[ci][dt][dh];
            if (q == 0) ac0 += p;
            else if (q == 1) ac1 += p;
            else if (q == 2) ac2 += p;
            else ac3 += p;
          }
        }
      float a = ((ac0 + ac1) + (ac2 + ac3)) + bias;
      a = fmaxf(a, 0.0f);
      y = fmaf(DEC, y, a);
      float s = (y >= 1.0f) ? 1.0f : 0.0f;
      if (t >= tstore) {
        float dlt = (t == 0) ? 0.0f : (s - sprev);
        dsto[(long)t * HW] = (signed char)dlt;
      }
      sprev = s;
      y = (s != 0.0f) ? 0.0f : y;
      // slide: load tau = t+3 into slot (u+3)%5
      int tau = t + 3;
      bool tv = tau < T;
      const int slot2 = (u + 3) % 5;
#pragma unroll
      for (int ci = 0; ci < 2; ++ci)
#pragma unroll
        for (int dh = 0; dh < 5; ++dh)
          win[ci][dh][slot2] = tv ? base[ci][dh][(long)tau * HW] : 0.0f;
    }
  }
}

// ---------------------------------------------------------------------------
// Kernel B: deconv(2x2,s2) + bias + relu + conv2(1x1) + LIF2 -> out
// out layout [B,2,H',W',T'], T' innermost; LDS-staged transposed flush.
// block = 64 threads (lane = w'), fixed (b,h',chunk of T').
// ---------------------------------------------------------------------------
__global__ void __launch_bounds__(64) stage2_kernel(
    const signed char* __restrict__ d8, const float* __restrict__ dw,
    const float* __restrict__ db, const float* __restrict__ cw,
    const float* __restrict__ cb, float* __restrict__ out) {
  __shared__ float SB[2][64][17];
  int bid   = blockIdx.x;
  int chunk = bid & 7;            // 8 chunks over T'=700
  int rest  = bid >> 3;
  int hp = rest & 127;            // h'
  int b  = rest >> 7;
  int wp = threadIdx.x;           // w'

  int h  = hp >> 1;
  int kh = 1 - (hp & 1);

  // deconv weights for this kh, both kt parities: dwk{kt}[c][ci]
  float dwk0[2][8], dwk1[2][8];
#pragma unroll
  for (int c = 0; c < 2; ++c)
#pragma unroll
    for (int ci = 0; ci < 8; ++ci) {
      dwk0[c][ci] = dw[((c * 8 + ci) * 2 + 0) * 2 + kh];
      dwk1[c][ci] = dw[((c * 8 + ci) * 2 + 1) * 2 + kh];
    }
  float db0 = db[0], db1 = db[1];
  float cw00 = cw[0], cw01 = cw[1], cw10 = cw[2], cw11 = cw[3];
  float cb0 = cb[0], cb1 = cb[1];

  int t0 = chunk * 88;
  int t1 = (t0 + 88 < TO) ? t0 + 88 : TO;   // last chunk: 84
  int tw = (t0 - 32 > 0) ? t0 - 32 : 0;     // 32-step LIF2 warm-up (even)

  const signed char* dbase = d8 + ((long)b * C1 * T) * HW + h * 64 + wp;
  float* outb = out + ((long)b * 2 * HO) * (long)(WO * TO);

  float y0 = 0.0f, y1 = 0.0f;
  float dv[8];
  for (int tp = tw; tp < t1; tp += 2) {
    int t = tp >> 1;
#pragma unroll
    for (int ci = 0; ci < 8; ++ci)
      dv[ci] = (float)dbase[((long)(ci * T + t)) * HW];

#pragma unroll
    for (int par = 0; par < 2; ++par) {     // par=0: tp (kt=1), par=1: tp+1 (kt=0)
      int tpp = tp + par;
      float v0 = db0, v1 = db1;
      if (par == 0) {
#pragma unroll
        for (int ci = 0; ci < 8; ++ci) {
          v0 = fmaf(dv[ci], dwk1[0][ci], v0);
          v1 = fmaf(dv[ci], dwk1[1][ci], v1);
        }
      } else {
#pragma unroll
        for (int ci = 0; ci < 8; ++ci) {
          v0 = fmaf(dv[ci], dwk0[0][ci], v0);
          v1 = fmaf(dv[ci], dwk0[1][ci], v1);
        }
      }
      v0 = fmaxf(v0, 0.0f);
      v1 = fmaxf(v1, 0.0f);
      float u0 = fmaf(cw00, v0, fmaf(cw01, v1, cb0));
      float u1 = fmaf(cw10, v0, fmaf(cw11, v1, cb1));
      y0 = fmaf(DEC, y0, u0);
      y1 = fmaf(DEC, y1, u1);
      float s0 = (y0 >= 1.0f) ? 1.0f : 0.0f;
      float s1 = (y1 >= 1.0f) ? 1.0f : 0.0f;
      y0 = (s0 != 0.0f) ? 0.0f : y0;
      y1 = (s1 != 0.0f) ? 0.0f : y1;

      if (tpp >= t0) {
        int k = (tpp - t0) & 15;
        SB[0][wp][k] = s0;
        SB[1][wp][k] = s1;
        if (par == 1 && (k == 15 || tpp == t1 - 1)) {
          __syncthreads();
          int Kc   = k + 1;                 // 16, 8, or 4 (all mod-4)
          int t0f  = tpp - k;
          int iters = Kc >> 2;              // 4, 2, 1
          int sh = (iters == 4) ? 2 : ((iters == 2) ? 1 : 0);
#pragma unroll
          for (int o = 0; o < 2; ++o) {
            float* ob = outb + ((long)(o * HO + hp)) * (long)(WO * TO);
            for (int i = 0; i < iters; ++i) {
              int idx = (i << 6) + wp;
              int r   = idx >> sh;
              int c   = (idx & (iters - 1)) << 2;
              float4 vv;
              vv.x = SB[o][r][c + 0];
              vv.y = SB[o][r][c + 1];
              vv.z = SB[o][r][c + 2];
              vv.w = SB[o][r][c + 3];
              *reinterpret_cast<float4*>(ob + (long)r * TO + (t0f + c)) = vv;
            }
          }
          __syncthreads();
        }
      }
    }
  }
}

// ---------------------------------------------------------------------------
extern "C" void kernel_launch(void* const* d_in, const int* in_sizes, int n_in,
                              void* d_out, int out_size, void* d_ws, size_t ws_size,
                              hipStream_t stream) {
  const float* x  = (const float*)d_in[0];
  const float* w1 = (const float*)d_in[1];
  const float* b1 = (const float*)d_in[2];
  const float* dw = (const float*)d_in[3];
  const float* db = (const float*)d_in[4];
  const float* cw = (const float*)d_in[5];
  const float* cb = (const float*)d_in[6];
  float* out = (float*)d_out;

  float* xT = (float*)d_ws;                                   // 22.94 MB
  signed char* d8 = (signed char*)d_ws + (size_t)B * CIN * T * HW * 4;  // +22.94 MB

  // 1) transpose x -> xT
  transpose_kernel<<<dim3(B * CIN * H * 6), dim3(256), 0, stream>>>(x, xT);
  // 2) conv1+relu+LIF1+delta -> d8
  convlif_kernel<<<dim3(B * H * 2), dim3(512), 0, stream>>>(xT, w1, b1, d8);
  // 3) deconv+relu+conv2+LIF2 -> out
  stage2_kernel<<<dim3(B * HO * 8), dim3(64), 0, stream>>>(d8, dw, db, cw, cb, out);
}